// Round 1
// baseline (466.759 us; speedup 1.0000x reference)
//
#include <hip/hip_runtime.h>
#include <cstdint>

// Problem constants (B,N,H,D fixed by setup_inputs)
#define BB 2
#define NN 2048
#define HH 16
#define DD 128
#define BH 32   // BB*HH
#define NPROJ 7

typedef __bf16 bf16x8 __attribute__((ext_vector_type(8)));
typedef float f32x4 __attribute__((ext_vector_type(4)));

__device__ __forceinline__ unsigned short f2bf(float f) {
  unsigned int u = __float_as_uint(f);
  u += 0x7fff + ((u >> 16) & 1);   // RN-even
  return (unsigned short)(u >> 16);
}

// ---------------------------------------------------------------------------
// 1) LSH hash of q and k rows. 8 lanes per row, fp64 accumulation (true sign
//    of the projection; borderline-zero projections are the only cross-impl
//    divergence risk). Output layout [B,H,N].
// ---------------------------------------------------------------------------
__global__ void hash_kernel(const float* __restrict__ q, const float* __restrict__ k,
                            const float* __restrict__ pd, int* __restrict__ qh,
                            int* __restrict__ kh) {
  __shared__ float spd[DD * NPROJ];
  for (int i = threadIdx.x; i < DD * NPROJ; i += 256) spd[i] = pd[i];
  __syncthreads();
  long long gid = (long long)blockIdx.x * 256 + threadIdx.x;
  int part = (int)(gid & 7);
  long long row = gid >> 3;                      // 0 .. 2*BB*NN*HH-1
  const long long NR = (long long)BB * NN * HH;
  int isk = row >= NR;
  long long r = isk ? row - NR : row;            // flat [b][n][h]
  const float* src = (isk ? k : q) + r * DD + part * 16;
  double acc[NPROJ];
  for (int p = 0; p < NPROJ; ++p) acc[p] = 0.0;
  for (int d = 0; d < 16; d += 4) {
    float4 x = *(const float4*)(src + d);
    int dbase = part * 16 + d;
    for (int p = 0; p < NPROJ; ++p) {
      acc[p] += (double)x.x * (double)spd[(dbase + 0) * NPROJ + p]
              + (double)x.y * (double)spd[(dbase + 1) * NPROJ + p]
              + (double)x.z * (double)spd[(dbase + 2) * NPROJ + p]
              + (double)x.w * (double)spd[(dbase + 3) * NPROJ + p];
    }
  }
  for (int off = 1; off < 8; off <<= 1)
    for (int p = 0; p < NPROJ; ++p) acc[p] += __shfl_xor(acc[p], off);
  if (part == 0) {
    int bin = 0;
    for (int p = 0; p < NPROJ; ++p) bin |= ((int)(acc[p] > 0.0)) << p;
    int hsh = bin ^ (bin >> 1);                  // _unit_hamming == Gray code
    int b_ = (int)(r / (NN * HH));
    int rem = (int)(r % (NN * HH));
    int n_ = rem / HH, h_ = rem % HH;
    (isk ? kh : qh)[((long long)b_ * HH + h_) * NN + n_] = hsh;
  }
}

// ---------------------------------------------------------------------------
// 2) Stable counting sort of q_hash per (b,h). 128 bins, 4 segments of 512.
//    Emits sort_idx and sorted hash values.
// ---------------------------------------------------------------------------
__global__ void sort_kernel(const int* __restrict__ qh, int* __restrict__ sidx,
                            int* __restrict__ qhs) {
  __shared__ int sh[NN];
  __shared__ int cnt[4][128];
  __shared__ int cum[128];
  int bh = blockIdx.x;
  const int* src = qh + (long long)bh * NN;
  for (int i = threadIdx.x; i < NN; i += 512) sh[i] = src[i];
  __syncthreads();
  int bin = threadIdx.x & 127, seg = threadIdx.x >> 7;
  int n0 = seg * (NN / 4);
  int c = 0;
  for (int n = n0; n < n0 + NN / 4; ++n) c += (sh[n] == bin);
  cnt[seg][bin] = c;
  __syncthreads();
  if (threadIdx.x == 0) {
    int run = 0;
    for (int t = 0; t < 128; ++t) {
      cum[t] = run;
      run += cnt[0][t] + cnt[1][t] + cnt[2][t] + cnt[3][t];
    }
  }
  __syncthreads();
  int pos = cum[bin];
  for (int s = 0; s < seg; ++s) pos += cnt[s][bin];
  for (int n = n0; n < n0 + NN / 4; ++n)
    if (sh[n] == bin) {
      sidx[(long long)bh * NN + pos] = n;
      qhs[(long long)bh * NN + pos] = bin;
      ++pos;
    }
}

// ---------------------------------------------------------------------------
// 3) keep[j] = OR over flat idx [j*1024,(j+1)*1024) of (q_hash_sort == k_hash)
//    (exactly the reference's reshape semantics on [B,H,N] flat buffers)
// ---------------------------------------------------------------------------
__global__ void keep_kernel(const int* __restrict__ qhs, const int* __restrict__ kh,
                            int* __restrict__ keep) {
  __shared__ int flag;
  if (threadIdx.x == 0) flag = 0;
  __syncthreads();
  int j = blockIdx.x;
  int m = 0;
  for (int t = threadIdx.x; t < 1024; t += 256)
    m |= (qhs[j * 1024 + t] == kh[j * 1024 + t]);
  if (m) flag = 1;
  __syncthreads();
  if (threadIdx.x == 0) keep[j] = flag;
}

// ---------------------------------------------------------------------------
// 4) Gather sorted Q rows -> bf16 [B,H,N,D]
// ---------------------------------------------------------------------------
__global__ void convert_q_kernel(const float* __restrict__ q, const int* __restrict__ sidx,
                                 unsigned short* __restrict__ Qs) {
  long long gid = (long long)blockIdx.x * 256 + threadIdx.x;
  int row = (int)(gid >> 5);          // bh*NN + qi
  int dg = (int)(gid & 31) * 4;
  int bh = row >> 11;
  int b = bh >> 4, h = bh & 15;
  int n = sidx[row];
  float4 x = *(const float4*)(q + (((long long)(b * NN + n) * HH + h) << 7) + dg);
  ushort4 y = make_ushort4(f2bf(x.x), f2bf(x.y), f2bf(x.z), f2bf(x.w));
  *(ushort4*)(Qs + (long long)row * DD + dg) = y;
}

// ---------------------------------------------------------------------------
// 5) K -> bf16 [B,H,N,D] with keep-zeroing (keep[h*4 + ki/512], batch-shared)
// ---------------------------------------------------------------------------
__global__ void convert_k_kernel(const float* __restrict__ k, const int* __restrict__ keep,
                                 unsigned short* __restrict__ Kc) {
  long long gid = (long long)blockIdx.x * 256 + threadIdx.x;
  int row = (int)(gid >> 5);
  int dg = (int)(gid & 31) * 4;
  int bh = row >> 11, ki = row & 2047;
  int b = bh >> 4, h = bh & 15;
  int kp = keep[h * 4 + (ki >> 9)];
  ushort4 y;
  if (kp) {
    float4 x = *(const float4*)(k + (((long long)(b * NN + ki) * HH + h) << 7) + dg);
    y = make_ushort4(f2bf(x.x), f2bf(x.y), f2bf(x.z), f2bf(x.w));
  } else {
    y = make_ushort4(0, 0, 0, 0);
  }
  *(ushort4*)(Kc + (long long)row * DD + dg) = y;
}

// ---------------------------------------------------------------------------
// 6) V -> bf16 transposed [B,H,D,N] (so PV B-fragments are contiguous)
// ---------------------------------------------------------------------------
__global__ void convert_v_kernel(const float* __restrict__ v, unsigned short* __restrict__ Vt) {
  __shared__ __align__(16) unsigned short tile[64][132];
  int bh = blockIdx.x >> 5;
  int n0 = (blockIdx.x & 31) * 64;
  int b = bh >> 4, h = bh & 15;
  for (int it = 0; it < 8; ++it) {
    int cid = it * 256 + threadIdx.x;
    int r = cid >> 5, d4 = (cid & 31) * 4;
    float4 x = *(const float4*)(v + (((long long)(b * NN + n0 + r) * HH + h) << 7) + d4);
    *(ushort4*)&tile[r][d4] = make_ushort4(f2bf(x.x), f2bf(x.y), f2bf(x.z), f2bf(x.w));
  }
  __syncthreads();
  for (int it = 0; it < 8; ++it) {
    int cid = it * 256 + threadIdx.x;
    int d = cid >> 4, n4 = (cid & 15) * 4;
    ushort4 y = make_ushort4(tile[n4 + 0][d], tile[n4 + 1][d], tile[n4 + 2][d], tile[n4 + 3][d]);
    *(ushort4*)(Vt + ((long long)bh * DD + d) * NN + n0 + n4) = y;
  }
}

// ---------------------------------------------------------------------------
// 7) Flash attention over sorted Q. 4 waves/block, 16 q rows/wave, 64-key
//    LDS tiles. S^T = K*Q^T (C layout: row=key=(lane>>4)*4+reg, col=q=lane&15),
//    online softmax (stats per q=lane&15), P round-trip through per-wave LDS
//    into A-layout, O = P*V with V^T[d][key] tiles. Scatter-unsort on store.
// ---------------------------------------------------------------------------
__global__ __launch_bounds__(256) void flash_kernel(
    const unsigned short* __restrict__ Qs, const unsigned short* __restrict__ Kc,
    const unsigned short* __restrict__ Vt, const int* __restrict__ sidx,
    float* __restrict__ out) {
  __shared__ __align__(16) unsigned short Kt[64 * 136];   // keys x d (+8 pad)
  __shared__ __align__(16) unsigned short Vs[128 * 72];   // d x keys (+8 pad)
  __shared__ __align__(16) unsigned short Pb[4][16 * 72]; // per-wave q x keys

  int qt = blockIdx.x, bh = blockIdx.y;
  int b = bh >> 4, h = bh & 15;
  int tid = threadIdx.x;
  int w = tid >> 6, lane = tid & 63;
  int l16 = lane & 15, qd = lane >> 4;
  int qrow = qt * 64 + w * 16 + l16;   // sorted q position for this lane's stats col

  bf16x8 qf[4];
  {
    const unsigned short* qb = Qs + ((long long)bh * NN + qrow) * DD;
    for (int c = 0; c < 4; ++c) qf[c] = *(const bf16x8*)(qb + c * 32 + qd * 8);
  }
  f32x4 o[8];
  for (int i = 0; i < 8; ++i) o[i] = (f32x4){0.f, 0.f, 0.f, 0.f};
  float m = -__builtin_inff(), l = 0.f;
  const float scale = 0.088388347648318447f;  // 128^-0.5

  for (int kb = 0; kb <= qt; ++kb) {
    int k0 = kb * 64;
    {
      const unsigned short* kg = Kc + ((long long)bh * NN + k0) * DD;
      for (int it = 0; it < 4; ++it) {
        int cid = it * 256 + tid;
        int r = cid >> 4, c8 = (cid & 15) * 8;
        *(uint4*)&Kt[r * 136 + c8] = *(const uint4*)(kg + r * DD + c8);
      }
      const unsigned short* vg = Vt + (long long)bh * DD * NN + k0;
      for (int it = 0; it < 4; ++it) {
        int cid = it * 256 + tid;
        int r = cid >> 3, c8 = (cid & 7) * 8;
        *(uint4*)&Vs[r * 72 + c8] = *(const uint4*)(vg + (long long)r * NN + c8);
      }
    }
    __syncthreads();

    // S^T = K * Q^T over this 64-key tile (4 key-subtiles of 16)
    float s[16];
    for (int t = 0; t < 4; ++t) {
      f32x4 acc = (f32x4){0.f, 0.f, 0.f, 0.f};
      for (int c = 0; c < 4; ++c) {
        bf16x8 kf = *(const bf16x8*)&Kt[(t * 16 + l16) * 136 + c * 32 + qd * 8];
        acc = __builtin_amdgcn_mfma_f32_16x16x32_bf16(kf, qf[c], acc, 0, 0, 0);
      }
      for (int r = 0; r < 4; ++r) {
        int keyg = k0 + t * 16 + qd * 4 + r;
        s[t * 4 + r] = (keyg > qrow) ? -__builtin_inff() : acc[r] * scale;
      }
    }
    // online softmax (stats per q = lane&15, replicated across quads)
    float mloc = s[0];
    for (int i = 1; i < 16; ++i) mloc = fmaxf(mloc, s[i]);
    mloc = fmaxf(mloc, __shfl_xor(mloc, 16));
    mloc = fmaxf(mloc, __shfl_xor(mloc, 32));
    float mnew = fmaxf(m, mloc);
    float alpha = __expf(m - mnew);
    float psum = 0.f;
    for (int t = 0; t < 4; ++t) {
      float p0 = __expf(s[t * 4 + 0] - mnew);
      float p1 = __expf(s[t * 4 + 1] - mnew);
      float p2 = __expf(s[t * 4 + 2] - mnew);
      float p3 = __expf(s[t * 4 + 3] - mnew);
      psum += (p0 + p1) + (p2 + p3);
      *(ushort4*)&Pb[w][l16 * 72 + t * 16 + qd * 4] =
          make_ushort4(f2bf(p0), f2bf(p1), f2bf(p2), f2bf(p3));
    }
    psum += __shfl_xor(psum, 16);
    psum += __shfl_xor(psum, 32);
    l = l * alpha + psum;
    m = mnew;
    // rescale O (O rows are q = qd*4+reg -> broadcast alpha from lanes 0..15)
    float aO[4];
    for (int r = 0; r < 4; ++r) aO[r] = __shfl(alpha, qd * 4 + r);
    for (int c8 = 0; c8 < 8; ++c8)
      for (int r = 0; r < 4; ++r) o[c8][r] *= aO[r];
    // O += P * V  (two K-dim=32 groups)
    for (int g = 0; g < 2; ++g) {
      bf16x8 pf = *(const bf16x8*)&Pb[w][l16 * 72 + g * 32 + qd * 8];
      for (int c8 = 0; c8 < 8; ++c8) {
        bf16x8 vf = *(const bf16x8*)&Vs[(c8 * 16 + l16) * 72 + g * 32 + qd * 8];
        o[c8] = __builtin_amdgcn_mfma_f32_16x16x32_bf16(pf, vf, o[c8], 0, 0, 0);
      }
    }
    __syncthreads();
  }

  // epilogue: normalize and scatter-unsort
  float lO[4];
  int nO[4];
  for (int r = 0; r < 4; ++r) {
    lO[r] = __shfl(l, qd * 4 + r);
    nO[r] = sidx[(long long)bh * NN + qt * 64 + w * 16 + qd * 4 + r];
  }
  for (int r = 0; r < 4; ++r) {
    float inv = 1.f / lO[r];
    float* ob = out + (((long long)(b * NN + nO[r]) * HH + h) << 7) + l16;
    for (int c8 = 0; c8 < 8; ++c8) ob[c8 * 16] = o[c8][r] * inv;
  }
}

// ---------------------------------------------------------------------------
// Workspace layout (bytes):
//   0        : q_hash   [B,H,N] int   (256 KiB)
//   256 KiB  : k_hash                 (256 KiB)
//   512 KiB  : sort_idx               (256 KiB)
//   768 KiB  : q_hash_sort            (256 KiB)
//   1 MiB    : keep[64] int
//   2 MiB    : Qs bf16 [B,H,N,D]      (16 MiB)
//   18 MiB   : Kc bf16 [B,H,N,D]      (16 MiB)
//   34 MiB   : Vt bf16 [B,H,D,N]      (16 MiB)   total 50 MiB
// ---------------------------------------------------------------------------
extern "C" void kernel_launch(void* const* d_in, const int* in_sizes, int n_in,
                              void* d_out, int out_size, void* d_ws, size_t ws_size,
                              hipStream_t stream) {
  const float* q = (const float*)d_in[0];
  const float* k = (const float*)d_in[1];
  const float* v = (const float*)d_in[2];
  const float* pd = (const float*)d_in[3];
  float* out = (float*)d_out;
  char* ws = (char*)d_ws;
  int* qh   = (int*)(ws + 0);
  int* kh   = (int*)(ws + (1u << 18));
  int* sidx = (int*)(ws + (2u << 18));
  int* qhs  = (int*)(ws + 3u * (1u << 18));
  int* keep = (int*)(ws + (1u << 20));
  unsigned short* Qs = (unsigned short*)(ws + (2u << 20));
  unsigned short* Kc = (unsigned short*)(ws + (18u << 20));
  unsigned short* Vt = (unsigned short*)(ws + (34u << 20));

  hash_kernel<<<4096, 256, 0, stream>>>(q, k, pd, qh, kh);
  sort_kernel<<<32, 512, 0, stream>>>(qh, sidx, qhs);
  keep_kernel<<<64, 256, 0, stream>>>(qhs, kh, keep);
  convert_q_kernel<<<8192, 256, 0, stream>>>(q, sidx, Qs);
  convert_k_kernel<<<8192, 256, 0, stream>>>(k, keep, Kc);
  convert_v_kernel<<<1024, 256, 0, stream>>>(v, Vt);
  flash_kernel<<<dim3(32, 32), 256, 0, stream>>>(Qs, Kc, Vt, sidx, out);
}